// Round 9
// baseline (2075.002 us; speedup 1.0000x reference)
//
#include <hip/hip_runtime.h>
#include <hip/hip_bf16.h>
#include <stdint.h>

// Problem constants
#define NN 32768
#define KNBR 32

typedef __attribute__((ext_vector_type(8))) short short8;
typedef __attribute__((ext_vector_type(4))) float f32x4;

__device__ __forceinline__ unsigned int f2bf(float x) {
    union { float f; unsigned int u; } c; c.f = x;
    return (c.u + 0x7FFFu + ((c.u >> 16) & 1u)) >> 16;
}
__device__ __forceinline__ unsigned int pk2(float a, float b) {
    return f2bf(a) | (f2bf(b) << 16);
}
// cheap round-half-up bf16 pack (validated: absmax 0.125 in r2-r8)
__device__ __forceinline__ unsigned int pkr(float a, float b) {
    unsigned ua = __float_as_uint(a) + 0x8000u;
    unsigned ub = __float_as_uint(b) + 0x8000u;
    return (ua >> 16) | (ub & 0xFFFF0000u);
}
__device__ __forceinline__ short8 cvt8(const float4& a, const float4& b) {
    union { unsigned u[4]; short8 s; } r;
    r.u[0] = pkr(a.x, a.y); r.u[1] = pkr(a.z, a.w);
    r.u[2] = pkr(b.x, b.y); r.u[3] = pkr(b.z, b.w);
    return r.s;
}
__device__ __forceinline__ float silu_f(float x) {
    return x / (1.0f + __expf(-x));
}

// ---------------------------------------------------------------------------
// Kernel 1: convert W_f2, W_nb, W_c (f32 [256][256]) into bf16 MFMA B-frag
// layout: frag q = (kt*16 + ntg)*64 + lane holds
// B[k = kt*32 + (lane>>4)*8 + i][col = ntg*16 + (lane&15)], i=0..7.
// ---------------------------------------------------------------------------
__global__ void prep_weights(const float* __restrict__ Wf2,
                             const float* __restrict__ Wnb,
                             const float* __restrict__ Wc,
                             uint4* __restrict__ ws_out) {
    int t = blockIdx.x * 256 + threadIdx.x;   // 0..24575
    int w = t >> 13;
    int q = t & 8191;
    int kt = q >> 10;
    int nt = (q >> 6) & 15;
    int lane = q & 63;
    int k0 = kt * 32 + ((lane >> 4) << 3);
    int col = nt * 16 + (lane & 15);
    const float* src = (w == 0) ? Wf2 : (w == 1) ? Wnb : Wc;
    const float* p = src + (size_t)k0 * 256 + col;
    uint4 o;
    o.x = pk2(p[0],        p[256]);
    o.y = pk2(p[512],      p[768]);
    o.z = pk2(p[1024],     p[1280]);
    o.w = pk2(p[1536],     p[1792]);
    ws_out[t] = o;
}

// ---------------------------------------------------------------------------
// Kernel 1b: precompute f = silu(diff @ Wf1 + b1) for ALL 1M edge rows,
// written as bf16 MFMA A-fragments (verified r8):
//   fout[(g128*8 + kt)*512 + mt*64 + lane] holds
//   f[row = g128*128 + mt*16 + (lane&15)][k = kt*32 + (lane>>4)*8 .. +8]
// ---------------------------------------------------------------------------
__global__ __launch_bounds__(256) void prep_f(
        const float* __restrict__ diff,   // [1M, 4]
        const float* __restrict__ Wf1,    // [4,256]
        const float* __restrict__ b1,     // [256]
        uint4* __restrict__ fout)
{
    const int bid  = blockIdx.x;          // g128*8 + kt
    const int kt   = bid & 7;
    const size_t g128 = (size_t)(bid >> 3);
    const int tid  = threadIdx.x;
    const int lane = tid & 63;
    const int wv   = tid >> 6;            // 0..3
    const int kgrp = lane >> 4, r16 = lane & 15;
    const int k0   = kt * 32 + kgrp * 8;

    float4 cwa[4], cwb[4];
    #pragma unroll
    for (int j = 0; j < 4; ++j) {
        cwa[j] = *(const float4*)(Wf1 + j * 256 + k0);
        cwb[j] = *(const float4*)(Wf1 + j * 256 + k0 + 4);
    }
    const float4 cba = *(const float4*)(b1 + k0);
    const float4 cbb = *(const float4*)(b1 + k0 + 4);

    #pragma unroll
    for (int mi = 0; mi < 2; ++mi) {
        const int mt = mi * 4 + wv;
        const size_t row = g128 * 128 + mt * 16 + r16;
        const float4 d = *(const float4*)(diff + row * 4);
        float v0 = cba.x + d.x*cwa[0].x + d.y*cwa[1].x + d.z*cwa[2].x + d.w*cwa[3].x;
        float v1 = cba.y + d.x*cwa[0].y + d.y*cwa[1].y + d.z*cwa[2].y + d.w*cwa[3].y;
        float v2 = cba.z + d.x*cwa[0].z + d.y*cwa[1].z + d.z*cwa[2].z + d.w*cwa[3].z;
        float v3 = cba.w + d.x*cwa[0].w + d.y*cwa[1].w + d.z*cwa[2].w + d.w*cwa[3].w;
        float v4 = cbb.x + d.x*cwb[0].x + d.y*cwb[1].x + d.z*cwb[2].x + d.w*cwb[3].x;
        float v5 = cbb.y + d.x*cwb[0].y + d.y*cwb[1].y + d.z*cwb[2].y + d.w*cwb[3].y;
        float v6 = cbb.z + d.x*cwb[0].z + d.y*cwb[1].z + d.z*cwb[2].z + d.w*cwb[3].z;
        float v7 = cbb.w + d.x*cwb[0].w + d.y*cwb[1].w + d.z*cwb[2].w + d.w*cwb[3].w;
        uint4 o;
        o.x = pkr(silu_f(v0), silu_f(v1));
        o.y = pkr(silu_f(v2), silu_f(v3));
        o.z = pkr(silu_f(v4), silu_f(v5));
        o.w = pkr(silu_f(v6), silu_f(v7));
        fout[(size_t)bid * 512 + mt * 64 + lane] = o;
    }
}

// ---------------------------------------------------------------------------
// Kernel 2: fused edge pipeline — ZERO barriers in the main loop.
// Weights RESIDENT in LDS (128KB, staged once; r6 XCD col-half pairing).
// f A-frags streamed from global (prep_f layout). E A-frags loaded DIRECTLY
// from global in fragment layout (lane = row(l&15) x k-octet(l>>4), 128B
// row segments; 4 wn-waves share addresses -> L1 broadcast) and converted
// f32->bf16 in registers. 1024 thr = 16 waves (4M x 4N), 128-row tiles.
// ---------------------------------------------------------------------------
__global__ __launch_bounds__(1024, 4) void msg_kernel(
        const float* __restrict__ nbr,    // h_neighbors [N*K, 256]
        const float* __restrict__ b2,     // b_f2 [256]
        const float* __restrict__ bnb,    // b_nb [256]
        const uint4* __restrict__ wf2_g,  // frag bf16, 8192 uint4
        const uint4* __restrict__ wnb_g,  // frag bf16, 8192 uint4
        const uint4* __restrict__ ffrag,  // f A-frags (prep_f output)
        float* __restrict__ msg_out)      // [N,256] f32
{
    __shared__ uint4 w2l[4096];        // 64KB  Wf2, this block's 128 cols
    __shared__ uint4 wnl[4096];        // 64KB  Wnb

    const int tid  = threadIdx.x;
    const int lane = tid & 63;
    const int wid  = tid >> 6;        // 0..15
    const int wm   = wid >> 2;        // 0..3  (32-row slice)
    const int wn   = wid & 3;         // 0..3  (32-col slice)
    const int xcd  = blockIdx.x & 7;
    const int yy   = blockIdx.x >> 3;
    const int chalf = yy & 1;
    const int rgrp  = xcd * 32 + (yy >> 1);          // 0..255
    const size_t rowbase = (size_t)rgrp * 4096;
    const int colbase = chalf * 128;

    // ---- stage weights once ----
    #pragma unroll
    for (int i = 0; i < 4; ++i) {
        int idx = tid + i * 1024;
        int kt = idx >> 9, rem = idx & 511;
        int src = kt * 1024 + chalf * 512 + rem;
        w2l[idx] = wf2_g[src];
        wnl[idx] = wnb_g[src];
    }
    float vb2[2], vbn[2];
    #pragma unroll
    for (int n = 0; n < 2; ++n) {
        const int col = colbase + wn * 32 + n * 16 + (lane & 15);
        vb2[n] = b2[col];
        vbn[n] = bnb[col];
    }
    __syncthreads();    // the ONLY block-wide barrier

    // ---- per-wave global A addressing ----
    // E frag m: row = wm*32 + m*16 + (lane&15), k = kt*32 + (lane>>4)*8 (+0..7)
    const float* ebase = nbr + (rowbase + wm * 32 + (lane & 15)) * 256
                         + ((lane >> 4) << 3);
    const short8* fbase = (const short8*)ffrag;

    auto eload4 = [&](int g, float4* v) {
        const float* p = ebase + (size_t)(g >> 3) * 32768 + (g & 7) * 32;
        v[0] = *(const float4*)p;
        v[1] = *(const float4*)(p + 4);
        v[2] = *(const float4*)(p + 4096);     // +16 rows
        v[3] = *(const float4*)(p + 4100);
    };
    auto fload = [&](int g, short8& a0, short8& a1) {
        const size_t fb = (size_t)(rgrp * 256 + g) * 512;   // (rgrp*32 + t)*8 + kt
        a0 = fbase[fb + (wm * 2 + 0) * 64 + lane];
        a1 = fbase[fb + (wm * 2 + 1) * 64 + lane];
    };

    f32x4 accP[2][2], accH[2][2];
    #pragma unroll
    for (int m = 0; m < 2; ++m)
        #pragma unroll
        for (int n = 0; n < 2; ++n) {
            accP[m][n] = (f32x4){0.f, 0.f, 0.f, 0.f};
            accH[m][n] = (f32x4){0.f, 0.f, 0.f, 0.f};
        }

    const short8* w28 = (const short8*)w2l;
    const short8* wn8 = (const short8*)wnl;

    short8 aF0c, aF1c, aF0n, aF1n;
    float4 Ec[4], En[4];
    fload(0, aF0c, aF1c);
    eload4(0, Ec);

    for (int t = 0; t < 32; ++t) {
        #pragma unroll
        for (int kt = 0; kt < 8; ++kt) {
            const int g = t * 8 + kt;
            // prefetch next step (global; no barrier -> stays in flight)
            if (g + 1 < 256) {
                fload(g + 1, aF0n, aF1n);
                eload4(g + 1, En);
            }
            // convert current E to bf16 frags
            short8 aE0 = cvt8(Ec[0], Ec[1]);
            short8 aE1 = cvt8(Ec[2], Ec[3]);
            // B frags from resident LDS
            short8 B20 = w28[(kt * 8 + wn * 2 + 0) * 64 + lane];
            short8 B21 = w28[(kt * 8 + wn * 2 + 1) * 64 + lane];
            short8 Bn0 = wn8[(kt * 8 + wn * 2 + 0) * 64 + lane];
            short8 Bn1 = wn8[(kt * 8 + wn * 2 + 1) * 64 + lane];
            accP[0][0] = __builtin_amdgcn_mfma_f32_16x16x32_bf16(aF0c, B20, accP[0][0], 0, 0, 0);
            accP[0][1] = __builtin_amdgcn_mfma_f32_16x16x32_bf16(aF0c, B21, accP[0][1], 0, 0, 0);
            accP[1][0] = __builtin_amdgcn_mfma_f32_16x16x32_bf16(aF1c, B20, accP[1][0], 0, 0, 0);
            accP[1][1] = __builtin_amdgcn_mfma_f32_16x16x32_bf16(aF1c, B21, accP[1][1], 0, 0, 0);
            accH[0][0] = __builtin_amdgcn_mfma_f32_16x16x32_bf16(aE0, Bn0, accH[0][0], 0, 0, 0);
            accH[0][1] = __builtin_amdgcn_mfma_f32_16x16x32_bf16(aE0, Bn1, accH[0][1], 0, 0, 0);
            accH[1][0] = __builtin_amdgcn_mfma_f32_16x16x32_bf16(aE1, Bn0, accH[1][0], 0, 0, 0);
            accH[1][1] = __builtin_amdgcn_mfma_f32_16x16x32_bf16(aE1, Bn1, accH[1][1], 0, 0, 0);
            // per-tile epilogue: gate + 32-row reduce + store (verified map)
            if (kt == 7) {
                const size_t node = (size_t)rgrp * 128 + t * 4 + wm;
                #pragma unroll
                for (int n = 0; n < 2; ++n) {
                    float sv = 0.f;
                    #pragma unroll
                    for (int m = 0; m < 2; ++m)
                        #pragma unroll
                        for (int r = 0; r < 4; ++r)
                            sv += (accP[m][n][r] + vb2[n]) * (accH[m][n][r] + vbn[n]);
                    sv += __shfl_xor(sv, 16);
                    sv += __shfl_xor(sv, 32);
                    if (lane < 16)
                        msg_out[node * 256 + colbase + wn * 32 + n * 16 + lane] = sv;
                }
                #pragma unroll
                for (int m = 0; m < 2; ++m)
                    #pragma unroll
                    for (int n = 0; n < 2; ++n) {
                        accP[m][n] = (f32x4){0.f, 0.f, 0.f, 0.f};
                        accH[m][n] = (f32x4){0.f, 0.f, 0.f, 0.f};
                    }
            }
            // rotate pipeline regs
            aF0c = aF0n; aF1c = aF1n;
            Ec[0] = En[0]; Ec[1] = En[1]; Ec[2] = En[2]; Ec[3] = En[3];
        }
    }
}

// ---------------------------------------------------------------------------
// Kernel 3: out = silu(h_center @ Wc + bc + msg), msg lives in `out` already.
// ---------------------------------------------------------------------------
__global__ __launch_bounds__(256) void out_kernel(
        const float* __restrict__ hc,     // [N,256]
        const float* __restrict__ bc,     // [256]
        const uint4* __restrict__ wc_g,   // frag bf16, 8192 uint4
        float* __restrict__ out)          // [N,256], contains msg on entry
{
    __shared__ unsigned short a_s[4 * 2 * 64 * 8];    // 8KB
    __shared__ unsigned short wc_s[2 * 16 * 64 * 8];  // 32KB

    const int tid  = threadIdx.x;
    const int lane = tid & 63;
    const int wn   = tid >> 6;        // 0..3
    const int rblk = blockIdx.x * 64;

    f32x4 acc[4][4];
    #pragma unroll
    for (int mt = 0; mt < 4; ++mt)
        #pragma unroll
        for (int nt = 0; nt < 4; ++nt)
            acc[mt][nt] = (f32x4){0.f, 0.f, 0.f, 0.f};

    uint4* af4 = (uint4*)a_s;
    for (int kt2 = 0; kt2 < 4; ++kt2) {
        {
            int row = tid >> 2, quarter = tid & 3;
            const float* src = hc + (size_t)(rblk + row) * 256 + kt2 * 64 + quarter * 16;
            float4 v0 = *(const float4*)(src + 0);
            float4 v1 = *(const float4*)(src + 4);
            float4 v2 = *(const float4*)(src + 8);
            float4 v3 = *(const float4*)(src + 12);
            uint4 p0, p1;
            p0.x = pk2(v0.x, v0.y); p0.y = pk2(v0.z, v0.w);
            p0.z = pk2(v1.x, v1.y); p0.w = pk2(v1.z, v1.w);
            p1.x = pk2(v2.x, v2.y); p1.y = pk2(v2.z, v2.w);
            p1.z = pk2(v3.x, v3.y); p1.w = pk2(v3.z, v3.w);
            int mt = row >> 4, kti = quarter >> 1, fr = row & 15;
            int g0 = (quarter & 1) * 2;
            af4[(mt * 2 + kti) * 64 + g0 * 16 + fr]       = p0;
            af4[(mt * 2 + kti) * 64 + (g0 + 1) * 16 + fr] = p1;
            const uint4* srcw = wc_g + kt2 * 2048;
            uint4* dw = (uint4*)wc_s;
            #pragma unroll
            for (int j = 0; j < 8; ++j)
                dw[j * 256 + tid] = srcw[j * 256 + tid];
        }
        __syncthreads();
        #pragma unroll
        for (int kti = 0; kti < 2; ++kti) {
            short8 b[4];
            #pragma unroll
            for (int nt = 0; nt < 4; ++nt)
                b[nt] = *(const short8*)&wc_s[((kti * 16 + wn * 4 + nt) * 64 + lane) * 8];
            #pragma unroll
            for (int mt = 0; mt < 4; ++mt) {
                short8 a = *(const short8*)&a_s[((mt * 2 + kti) * 64 + lane) * 8];
                #pragma unroll
                for (int nt = 0; nt < 4; ++nt)
                    acc[mt][nt] = __builtin_amdgcn_mfma_f32_16x16x32_bf16(a, b[nt], acc[mt][nt], 0, 0, 0);
            }
        }
        __syncthreads();
    }

    #pragma unroll
    for (int mt = 0; mt < 4; ++mt)
        #pragma unroll
        for (int nt = 0; nt < 4; ++nt)
            #pragma unroll
            for (int r = 0; r < 4; ++r) {
                int grow = rblk + mt * 16 + ((lane >> 4) << 2) + r;
                int col  = wn * 64 + nt * 16 + (lane & 15);
                size_t idx = (size_t)grow * 256 + col;
                float v = acc[mt][nt][r] + bc[col] + out[idx];
                out[idx] = silu_f(v);
            }
}

// ---------------------------------------------------------------------------
extern "C" void kernel_launch(void* const* d_in, const int* in_sizes, int n_in,
                              void* d_out, int out_size, void* d_ws, size_t ws_size,
                              hipStream_t stream) {
    const float* h_center    = (const float*)d_in[0];
    const float* h_neighbors = (const float*)d_in[1];
    const float* differences = (const float*)d_in[2];
    const float* W_f1        = (const float*)d_in[3];
    const float* b_f1        = (const float*)d_in[4];
    const float* W_f2        = (const float*)d_in[5];
    const float* b_f2        = (const float*)d_in[6];
    const float* W_nb        = (const float*)d_in[7];
    const float* b_nb        = (const float*)d_in[8];
    const float* W_c         = (const float*)d_in[9];
    const float* b_c         = (const float*)d_in[10];
    float* out = (float*)d_out;

    uint4* ws4 = (uint4*)d_ws;
    const uint4* wf2_ws = ws4;            // [0, 8192)
    const uint4* wnb_ws = ws4 + 8192;     // [8192, 16384)
    const uint4* wc_ws  = ws4 + 16384;    // [16384, 24576)
    uint4* f_ws         = ws4 + 24576;    // 4,194,304 uint4 = 67MB

    prep_weights<<<96, 256, 0, stream>>>(W_f2, W_nb, W_c, ws4);
    prep_f<<<65536, 256, 0, stream>>>(differences, W_f1, b_f1, f_ws);
    msg_kernel<<<512, 1024, 0, stream>>>(
        h_neighbors, b_f2, b_nb, wf2_ws, wnb_ws, f_ws, out);
    out_kernel<<<NN / 64, 256, 0, stream>>>(h_center, b_c, wc_ws, out);
}

// Round 10
// 993.643 us; speedup vs baseline: 2.0883x; 2.0883x over previous
//
#include <hip/hip_runtime.h>
#include <hip/hip_bf16.h>
#include <stdint.h>

// Problem constants
#define NN 32768
#define KNBR 32

typedef __attribute__((ext_vector_type(8))) short short8;
typedef __attribute__((ext_vector_type(4))) float f32x4;

__device__ __forceinline__ unsigned int f2bf(float x) {
    union { float f; unsigned int u; } c; c.f = x;
    return (c.u + 0x7FFFu + ((c.u >> 16) & 1u)) >> 16;
}
__device__ __forceinline__ unsigned int pk2(float a, float b) {
    return f2bf(a) | (f2bf(b) << 16);
}
// cheap round-half-up bf16 pack (validated: absmax 0.125 in r2-r9)
__device__ __forceinline__ unsigned int pkr(float a, float b) {
    unsigned ua = __float_as_uint(a) + 0x8000u;
    unsigned ub = __float_as_uint(b) + 0x8000u;
    return (ua >> 16) | (ub & 0xFFFF0000u);
}
__device__ __forceinline__ float silu_f(float x) {
    return x / (1.0f + __expf(-x));
}

// ---------------------------------------------------------------------------
// Kernel 1: convert W_f2, W_nb, W_c (f32 [256][256]) into bf16 MFMA B-frag
// layout: frag q = (kt*16 + ntg)*64 + lane holds
// B[k = kt*32 + (lane>>4)*8 + i][col = ntg*16 + (lane&15)], i=0..7.
// ---------------------------------------------------------------------------
__global__ void prep_weights(const float* __restrict__ Wf2,
                             const float* __restrict__ Wnb,
                             const float* __restrict__ Wc,
                             uint4* __restrict__ ws_out) {
    int t = blockIdx.x * 256 + threadIdx.x;   // 0..24575
    int w = t >> 13;
    int q = t & 8191;
    int kt = q >> 10;
    int nt = (q >> 6) & 15;
    int lane = q & 63;
    int k0 = kt * 32 + ((lane >> 4) << 3);
    int col = nt * 16 + (lane & 15);
    const float* src = (w == 0) ? Wf2 : (w == 1) ? Wnb : Wc;
    const float* p = src + (size_t)k0 * 256 + col;
    uint4 o;
    o.x = pk2(p[0],        p[256]);
    o.y = pk2(p[512],      p[768]);
    o.z = pk2(p[1024],     p[1280]);
    o.w = pk2(p[1536],     p[1792]);
    ws_out[t] = o;
}

// ---------------------------------------------------------------------------
// Kernel 1b: precompute f = silu(diff @ Wf1 + b1) for ALL 1M edge rows,
// as bf16 MFMA A-fragments (verified r8/r9):
//   fout[(g128*8 + kt)*512 + mt*64 + lane] holds
//   f[row = g128*128 + mt*16 + (lane&15)][k = kt*32 + (lane>>4)*8 .. +8]
// ---------------------------------------------------------------------------
__global__ __launch_bounds__(256) void prep_f(
        const float* __restrict__ diff,   // [1M, 4]
        const float* __restrict__ Wf1,    // [4,256]
        const float* __restrict__ b1,     // [256]
        uint4* __restrict__ fout)
{
    const int bid  = blockIdx.x;          // g128*8 + kt
    const int kt   = bid & 7;
    const size_t g128 = (size_t)(bid >> 3);
    const int tid  = threadIdx.x;
    const int lane = tid & 63;
    const int wv   = tid >> 6;            // 0..3
    const int kgrp = lane >> 4, r16 = lane & 15;
    const int k0   = kt * 32 + kgrp * 8;

    float4 cwa[4], cwb[4];
    #pragma unroll
    for (int j = 0; j < 4; ++j) {
        cwa[j] = *(const float4*)(Wf1 + j * 256 + k0);
        cwb[j] = *(const float4*)(Wf1 + j * 256 + k0 + 4);
    }
    const float4 cba = *(const float4*)(b1 + k0);
    const float4 cbb = *(const float4*)(b1 + k0 + 4);

    #pragma unroll
    for (int mi = 0; mi < 2; ++mi) {
        const int mt = mi * 4 + wv;
        const size_t row = g128 * 128 + mt * 16 + r16;
        const float4 d = *(const float4*)(diff + row * 4);
        float v0 = cba.x + d.x*cwa[0].x + d.y*cwa[1].x + d.z*cwa[2].x + d.w*cwa[3].x;
        float v1 = cba.y + d.x*cwa[0].y + d.y*cwa[1].y + d.z*cwa[2].y + d.w*cwa[3].y;
        float v2 = cba.z + d.x*cwa[0].z + d.y*cwa[1].z + d.z*cwa[2].z + d.w*cwa[3].z;
        float v3 = cba.w + d.x*cwa[0].w + d.y*cwa[1].w + d.z*cwa[2].w + d.w*cwa[3].w;
        float v4 = cbb.x + d.x*cwb[0].x + d.y*cwb[1].x + d.z*cwb[2].x + d.w*cwb[3].x;
        float v5 = cbb.y + d.x*cwb[0].y + d.y*cwb[1].y + d.z*cwb[2].y + d.w*cwb[3].y;
        float v6 = cbb.z + d.x*cwb[0].z + d.y*cwb[1].z + d.z*cwb[2].z + d.w*cwb[3].z;
        float v7 = cbb.w + d.x*cwb[0].w + d.y*cwb[1].w + d.z*cwb[2].w + d.w*cwb[3].w;
        uint4 o;
        o.x = pkr(silu_f(v0), silu_f(v1));
        o.y = pkr(silu_f(v2), silu_f(v3));
        o.z = pkr(silu_f(v4), silu_f(v5));
        o.w = pkr(silu_f(v6), silu_f(v7));
        fout[(size_t)bid * 512 + mt * 64 + lane] = o;
    }
}

// ---------------------------------------------------------------------------
// Kernel 2: fused edge pipeline. 512 thr = 8 waves (2M x 4N); block owns a
// 64-col QUARTER -> resident weights 64KB; LDS total 73KB -> 2 blocks/CU
// (barrier of one block hidden by the other block's waves).
// Grid 1024 = 256 rowgroups x 4 col-quarters; swizzle: the 4 quarters of a
// rowgroup are consecutive on one XCD -> E rows fetched once to L2, read 4x.
// E: HBM->regs->bf16->LDS (linear writes, dbuf, 1 raw barrier/step).
// f: streamed from prep_f frags (global, L1-broadcast across wn waves).
// ---------------------------------------------------------------------------
__global__ __launch_bounds__(512, 4) void msg_kernel(
        const float* __restrict__ nbr,    // h_neighbors [N*K, 256]
        const float* __restrict__ b2,     // b_f2 [256]
        const float* __restrict__ bnb,    // b_nb [256]
        const uint4* __restrict__ wf2_g,  // frag bf16, 8192 uint4
        const uint4* __restrict__ wnb_g,  // frag bf16, 8192 uint4
        const uint4* __restrict__ ffrag,  // f A-frags (prep_f output)
        float* __restrict__ msg_out)      // [N,256] f32
{
    __shared__ uint4 w2l[2048];        // 32KB  Wf2, this block's 64 cols
    __shared__ uint4 wnl[2048];        // 32KB  Wnb
    __shared__ uint4 ebuf[2][512];     // 16KB  E A-frags (128r x 32k), dbuf

    const int tid  = threadIdx.x;
    const int lane = tid & 63;
    const int wid  = tid >> 6;        // 0..7
    const int wm   = wid >> 2;        // 0..1  (64-row slice)
    const int wn   = wid & 3;         // 0..3  (16-col slice)
    const int xcd  = blockIdx.x & 7;
    const int ii   = blockIdx.x >> 3; // 0..127
    const int rgrp = xcd * 32 + (ii >> 2);   // 0..255
    const int colq = ii & 3;
    const size_t rowbase = (size_t)rgrp * 4096;
    const int colbase = colq * 64;

    // ---- stage weights once (64 cols = ntg [colq*4, colq*4+4)) ----
    #pragma unroll
    for (int j = 0; j < 4; ++j) {
        int idx = tid + j * 512;                 // 0..2047
        int kt = idx >> 8, ln = (idx >> 6) & 3, la = idx & 63;
        int src = (kt * 16 + colq * 4 + ln) * 64 + la;
        w2l[idx] = wf2_g[src];
        wnl[idx] = wnb_g[src];
    }
    const float vb2 = b2[colbase + wn * 16 + (lane & 15)];
    const float vbn = bnb[colbase + wn * 16 + (lane & 15)];

    // ---- E staging: thread -> one frag slot (mt = tid>>6, lane) ----
    const int srow = (tid >> 6) * 16 + (lane & 15);   // 0..127
    const int skoct = (lane >> 4);                    // k-octet
    auto eload = [&](int g, float4& a, float4& b) {
        const float* p = nbr + (rowbase + (size_t)(g >> 3) * 128 + srow) * 256
                         + (g & 7) * 32 + skoct * 8;
        a = *(const float4*)p;
        b = *(const float4*)(p + 4);
    };
    auto ewrite = [&](int pb, const float4& a, const float4& b) {
        uint4 o;
        o.x = pkr(a.x, a.y); o.y = pkr(a.z, a.w);
        o.z = pkr(b.x, b.y); o.w = pkr(b.z, b.w);
        ebuf[pb][tid] = o;
    };
    const short8* fbase = (const short8*)ffrag;
    auto fload = [&](int g, short8* a) {
        const size_t fb = (size_t)(rgrp * 256 + g) * 512;
        #pragma unroll
        for (int m = 0; m < 4; ++m)
            a[m] = fbase[fb + (wm * 4 + m) * 64 + lane];
    };

    // ---- prologue ----
    float4 e0a, e0b;
    eload(0, e0a, e0b);
    ewrite(0, e0a, e0b);
    short8 aFc[4], aFn[4];
    fload(0, aFc);
    float4 EnA, EnB, EfA, EfB;
    eload(1, EnA, EnB);
    __syncthreads();

    f32x4 accP[4], accH[4];
    #pragma unroll
    for (int m = 0; m < 4; ++m) {
        accP[m] = (f32x4){0.f, 0.f, 0.f, 0.f};
        accH[m] = (f32x4){0.f, 0.f, 0.f, 0.f};
    }

    const short8* w28 = (const short8*)w2l;
    const short8* wn8 = (const short8*)wnl;

    for (int t = 0; t < 32; ++t) {
        #pragma unroll
        for (int kt = 0; kt < 8; ++kt) {
            const int g = t * 8 + kt;
            const int pb = g & 1;
            // prefetch: E 2 steps ahead, f 1 step ahead
            if (g + 2 < 256) eload(g + 2, EfA, EfB);
            if (g + 1 < 256) fload(g + 1, aFn);
            // current-step LDS reads
            const short8* eb8 = (const short8*)ebuf[pb];
            short8 B2 = w28[(kt * 4 + wn) * 64 + lane];
            short8 Bn = wn8[(kt * 4 + wn) * 64 + lane];
            short8 aE0 = eb8[(wm * 4 + 0) * 64 + lane];
            short8 aE1 = eb8[(wm * 4 + 1) * 64 + lane];
            short8 aE2 = eb8[(wm * 4 + 2) * 64 + lane];
            short8 aE3 = eb8[(wm * 4 + 3) * 64 + lane];
            accP[0] = __builtin_amdgcn_mfma_f32_16x16x32_bf16(aFc[0], B2, accP[0], 0, 0, 0);
            accP[1] = __builtin_amdgcn_mfma_f32_16x16x32_bf16(aFc[1], B2, accP[1], 0, 0, 0);
            accP[2] = __builtin_amdgcn_mfma_f32_16x16x32_bf16(aFc[2], B2, accP[2], 0, 0, 0);
            accP[3] = __builtin_amdgcn_mfma_f32_16x16x32_bf16(aFc[3], B2, accP[3], 0, 0, 0);
            accH[0] = __builtin_amdgcn_mfma_f32_16x16x32_bf16(aE0, Bn, accH[0], 0, 0, 0);
            accH[1] = __builtin_amdgcn_mfma_f32_16x16x32_bf16(aE1, Bn, accH[1], 0, 0, 0);
            accH[2] = __builtin_amdgcn_mfma_f32_16x16x32_bf16(aE2, Bn, accH[2], 0, 0, 0);
            accH[3] = __builtin_amdgcn_mfma_f32_16x16x32_bf16(aE3, Bn, accH[3], 0, 0, 0);
            // stage E for step g+1 into other buffer (vmcnt wait is counted)
            if (g + 1 < 256) ewrite(pb ^ 1, EnA, EnB);
            // per-tile epilogue: gate + 32-row reduce + store (verified map)
            if (kt == 7) {
                #pragma unroll
                for (int h = 0; h < 2; ++h) {
                    const size_t node = (size_t)rgrp * 128 + t * 4 + wm * 2 + h;
                    float sv = 0.f;
                    #pragma unroll
                    for (int m2 = 0; m2 < 2; ++m2) {
                        const int m = h * 2 + m2;
                        #pragma unroll
                        for (int r = 0; r < 4; ++r)
                            sv += (accP[m][r] + vb2) * (accH[m][r] + vbn);
                    }
                    sv += __shfl_xor(sv, 16);
                    sv += __shfl_xor(sv, 32);
                    if (lane < 16)
                        msg_out[node * 256 + colbase + wn * 16 + lane] = sv;
                }
                #pragma unroll
                for (int m = 0; m < 4; ++m) {
                    accP[m] = (f32x4){0.f, 0.f, 0.f, 0.f};
                    accH[m] = (f32x4){0.f, 0.f, 0.f, 0.f};
                }
            }
            // one raw barrier per step (LDS writes visible; vmcnt NOT drained)
            asm volatile("s_waitcnt lgkmcnt(0)" ::: "memory");
            __builtin_amdgcn_sched_barrier(0);
            __builtin_amdgcn_s_barrier();
            EnA = EfA; EnB = EfB;
            aFc[0] = aFn[0]; aFc[1] = aFn[1]; aFc[2] = aFn[2]; aFc[3] = aFn[3];
        }
    }
}

// ---------------------------------------------------------------------------
// Kernel 3: out = silu(h_center @ Wc + bc + msg), msg lives in `out` already.
// ---------------------------------------------------------------------------
__global__ __launch_bounds__(256) void out_kernel(
        const float* __restrict__ hc,     // [N,256]
        const float* __restrict__ bc,     // [256]
        const uint4* __restrict__ wc_g,   // frag bf16, 8192 uint4
        float* __restrict__ out)          // [N,256], contains msg on entry
{
    __shared__ unsigned short a_s[4 * 2 * 64 * 8];    // 8KB
    __shared__ unsigned short wc_s[2 * 16 * 64 * 8];  // 32KB

    const int tid  = threadIdx.x;
    const int lane = tid & 63;
    const int wn   = tid >> 6;        // 0..3
    const int rblk = blockIdx.x * 64;

    f32x4 acc[4][4];
    #pragma unroll
    for (int mt = 0; mt < 4; ++mt)
        #pragma unroll
        for (int nt = 0; nt < 4; ++nt)
            acc[mt][nt] = (f32x4){0.f, 0.f, 0.f, 0.f};

    uint4* af4 = (uint4*)a_s;
    for (int kt2 = 0; kt2 < 4; ++kt2) {
        {
            int row = tid >> 2, quarter = tid & 3;
            const float* src = hc + (size_t)(rblk + row) * 256 + kt2 * 64 + quarter * 16;
            float4 v0 = *(const float4*)(src + 0);
            float4 v1 = *(const float4*)(src + 4);
            float4 v2 = *(const float4*)(src + 8);
            float4 v3 = *(const float4*)(src + 12);
            uint4 p0, p1;
            p0.x = pk2(v0.x, v0.y); p0.y = pk2(v0.z, v0.w);
            p0.z = pk2(v1.x, v1.y); p0.w = pk2(v1.z, v1.w);
            p1.x = pk2(v2.x, v2.y); p1.y = pk2(v2.z, v2.w);
            p1.z = pk2(v3.x, v3.y); p1.w = pk2(v3.z, v3.w);
            int mt = row >> 4, kti = quarter >> 1, fr = row & 15;
            int g0 = (quarter & 1) * 2;
            af4[(mt * 2 + kti) * 64 + g0 * 16 + fr]       = p0;
            af4[(mt * 2 + kti) * 64 + (g0 + 1) * 16 + fr] = p1;
            const uint4* srcw = wc_g + kt2 * 2048;
            uint4* dw = (uint4*)wc_s;
            #pragma unroll
            for (int j = 0; j < 8; ++j)
                dw[j * 256 + tid] = srcw[j * 256 + tid];
        }
        __syncthreads();
        #pragma unroll
        for (int kti = 0; kti < 2; ++kti) {
            short8 b[4];
            #pragma unroll
            for (int nt = 0; nt < 4; ++nt)
                b[nt] = *(const short8*)&wc_s[((kti * 16 + wn * 4 + nt) * 64 + lane) * 8];
            #pragma unroll
            for (int mt = 0; mt < 4; ++mt) {
                short8 a = *(const short8*)&a_s[((mt * 2 + kti) * 64 + lane) * 8];
                #pragma unroll
                for (int nt = 0; nt < 4; ++nt)
                    acc[mt][nt] = __builtin_amdgcn_mfma_f32_16x16x32_bf16(a, b[nt], acc[mt][nt], 0, 0, 0);
            }
        }
        __syncthreads();
    }

    #pragma unroll
    for (int mt = 0; mt < 4; ++mt)
        #pragma unroll
        for (int nt = 0; nt < 4; ++nt)
            #pragma unroll
            for (int r = 0; r < 4; ++r) {
                int grow = rblk + mt * 16 + ((lane >> 4) << 2) + r;
                int col  = wn * 64 + nt * 16 + (lane & 15);
                size_t idx = (size_t)grow * 256 + col;
                float v = acc[mt][nt][r] + bc[col] + out[idx];
                out[idx] = silu_f(v);
            }
}

// ---------------------------------------------------------------------------
extern "C" void kernel_launch(void* const* d_in, const int* in_sizes, int n_in,
                              void* d_out, int out_size, void* d_ws, size_t ws_size,
                              hipStream_t stream) {
    const float* h_center    = (const float*)d_in[0];
    const float* h_neighbors = (const float*)d_in[1];
    const float* differences = (const float*)d_in[2];
    const float* W_f1        = (const float*)d_in[3];
    const float* b_f1        = (const float*)d_in[4];
    const float* W_f2        = (const float*)d_in[5];
    const float* b_f2        = (const float*)d_in[6];
    const float* W_nb        = (const float*)d_in[7];
    const float* b_nb        = (const float*)d_in[8];
    const float* W_c         = (const float*)d_in[9];
    const float* b_c         = (const float*)d_in[10];
    float* out = (float*)d_out;

    uint4* ws4 = (uint4*)d_ws;
    const uint4* wf2_ws = ws4;            // [0, 8192)
    const uint4* wnb_ws = ws4 + 8192;     // [8192, 16384)
    const uint4* wc_ws  = ws4 + 16384;    // [16384, 24576)
    uint4* f_ws         = ws4 + 24576;    // 4,194,304 uint4 = 67MB

    prep_weights<<<96, 256, 0, stream>>>(W_f2, W_nb, W_c, ws4);
    prep_f<<<65536, 256, 0, stream>>>(differences, W_f1, b_f1, f_ws);
    msg_kernel<<<1024, 512, 0, stream>>>(
        h_neighbors, b_f2, b_nb, wf2_ws, wnb_ws, f_ws, out);
    out_kernel<<<NN / 64, 256, 0, stream>>>(h_center, b_c, wc_ws, out);
}